// Round 3
// baseline (116.443 us; speedup 1.0000x reference)
//
#include <hip/hip_runtime.h>
#include <hip/hip_bf16.h>

#define BB 16
#define LL 2048
#define DD 64

typedef __attribute__((ext_vector_type(8))) short short8t;
typedef __attribute__((ext_vector_type(4))) float f32x4;
typedef __attribute__((ext_vector_type(4))) unsigned short ushort4t;

__device__ __forceinline__ unsigned short f2bf(float x) {
  union { float f; unsigned int u; } c; c.f = x;
  unsigned int u = c.u;
  u += 0x7fffu + ((u >> 16) & 1u);   // RNE; inputs are finite
  return (unsigned short)(u >> 16);
}

// fp32 -> bf16 elementwise (2M elements per tensor)
__global__ void cvt_bf16(const float* __restrict__ in, unsigned short* __restrict__ out) {
  int i = (blockIdx.x * 256 + threadIdx.x) * 4;
  float4 v = *(const float4*)(in + i);
  ushort4t o;
  o.x = f2bf(v.x); o.y = f2bf(v.y); o.z = f2bf(v.z); o.w = f2bf(v.w);
  *(ushort4t*)(out + i) = o;
}

// V [b][j][d] fp32 -> VT [b][d][j] bf16 (64x64 LDS tile transpose)
__global__ void vtrans(const float* __restrict__ v, unsigned short* __restrict__ vt) {
  __shared__ unsigned short t[64][66];
  int b = blockIdx.x >> 5, j0 = (blockIdx.x & 31) * 64;
  const float* src = v + ((size_t)b * LL + j0) * DD;
#pragma unroll
  for (int i = 0; i < 16; ++i) {
    int lin = i * 256 + threadIdx.x;
    int j = lin >> 6, d = lin & 63;
    t[j][d] = f2bf(src[lin]);
  }
  __syncthreads();
  unsigned short* dst = vt + (size_t)b * DD * LL;
#pragma unroll
  for (int i = 0; i < 16; ++i) {
    int lin = i * 256 + threadIdx.x;
    int d = lin >> 6, j = lin & 63;
    dst[(size_t)d * LL + j0 + j] = t[j][d];
  }
}

__device__ __forceinline__ void async_cp16(const unsigned short* src, unsigned short* dst_lds) {
  __builtin_amdgcn_global_load_lds(
      (const __attribute__((address_space(1))) unsigned int*)src,
      (__attribute__((address_space(3))) unsigned int*)dst_lds, 16, 0, 0);
}

// Block: 4 waves, 64 queries; each wave: all 64 q x its k-stripe (16 tiles of BK=32),
// wave-private LDS, software-pipelined (K double-buffered; V prefetch issued only
// after vf is register-resident — lgkmcnt fence).
__global__ void __launch_bounds__(256, 2)
attn_main(const unsigned short* __restrict__ Qb, const unsigned short* __restrict__ Kb,
          const unsigned short* __restrict__ VTb, const int* __restrict__ mask,
          float* __restrict__ out, float* __restrict__ attn) {
  __shared__ __align__(16) unsigned short TB[4][8192];  // per wave: K0,K1,V,P (16 KB)
  __shared__ float redL[4][64];
  __shared__ float rinvL[64];

  const int tid = threadIdx.x;
  const int w = tid >> 6;
  const int l = tid & 63;
  const int l15 = l & 15;
  const int g = l >> 4;

  const int b = blockIdx.x >> 5;
  const int q0 = (blockIdx.x & 31) << 6;

  unsigned short* K0 = &TB[w][0];
  unsigned short* K1 = &TB[w][2048];
  unsigned short* VB = &TB[w][4096];
  unsigned short* PB = &TB[w][6144];

  const unsigned short* Kbb = Kb + (size_t)b * LL * DD;
  const unsigned short* VTbb = VTb + (size_t)b * DD * LL;
  const int* maskb = mask + b * LL;

  auto loadK = [&](int k0, unsigned short* KB) {
    const unsigned short* gs = Kbb + (size_t)k0 * DD;
#pragma unroll
    for (int i2 = 0; i2 < 4; ++i2) {
      int row = i2 * 8 + (l >> 3);
      int ce = (l & 7) * 8;
      async_cp16(gs + row * 64 + (ce ^ ((row & 3) << 4)), KB + i2 * 512);
    }
  };
  auto loadV = [&](int k0) {
    const unsigned short* gs = VTbb + k0;
#pragma unroll
    for (int i2 = 0; i2 < 4; ++i2) {
      int row = i2 * 16 + (l >> 2);
      int ce = (l & 3) * 8;
      async_cp16(gs + (size_t)row * LL + (ce ^ ((row & 1) << 4)), VB + i2 * 512);
    }
  };

  // persistent Q fragments: row = q0+16*mi+l15, d = 32*h + 8*g + e
  short8t qf[4][2];
  {
    const unsigned short* qbase = Qb + ((size_t)b * LL + q0 + l15) * DD + 8 * g;
#pragma unroll
    for (int mi = 0; mi < 4; ++mi)
#pragma unroll
      for (int h = 0; h < 2; ++h)
        qf[mi][h] = *(const short8t*)(qbase + mi * 16 * DD + 32 * h);
  }

  float ls[4][4];
#pragma unroll
  for (int mi = 0; mi < 4; ++mi)
#pragma unroll
    for (int r = 0; r < 4; ++r) ls[mi][r] = 0.f;

  // ---------------- pass A: row sums of exp(s) ----------------
  auto stepA = [&](int t, int tn, unsigned short* KBc, unsigned short* KBn,
                   int mk0c, int mk1c, int& mk0n, int& mk1n) {
    asm volatile("s_waitcnt vmcnt(0)" ::: "memory");
    short8t kf[2][2];
#pragma unroll
    for (int ni = 0; ni < 2; ++ni)
#pragma unroll
      for (int h = 0; h < 2; ++h) {
        int row = 16 * ni + l15;
        int col = (32 * h + 8 * g) ^ ((l15 & 3) << 4);
        kf[ni][h] = *(const short8t*)(KBc + row * 64 + col);
      }
    loadK(tn * 32, KBn);
    mk0n = maskb[tn * 32 + l15];
    mk1n = maskb[tn * 32 + 16 + l15];

    f32x4 sacc[4][2] = {};
#pragma unroll
    for (int mi = 0; mi < 4; ++mi)
#pragma unroll
      for (int ni = 0; ni < 2; ++ni)
#pragma unroll
        for (int h = 0; h < 2; ++h)
          sacc[mi][ni] = __builtin_amdgcn_mfma_f32_16x16x32_bf16(qf[mi][h], kf[ni][h], sacc[mi][ni], 0, 0, 0);
#pragma unroll
    for (int mi = 0; mi < 4; ++mi)
#pragma unroll
      for (int ni = 0; ni < 2; ++ni) {
        int mk = ni ? mk1c : mk0c;
#pragma unroll
        for (int r = 0; r < 4; ++r) {
          float p = mk ? 0.f : __expf(sacc[mi][ni][r] * 0.125f);
          ls[mi][r] += p;
        }
      }
  };

  {
    loadK(w * 32, K0);
    int a0 = maskb[w * 32 + l15], a1 = maskb[w * 32 + 16 + l15];
    int b0, b1;
    for (int j = 0; j < 8; ++j) {
      int t = w + 8 * j;
      stepA(t, t + 4, K0, K1, a0, a1, b0, b1);
      int t2 = t + 4;
      int tn = (j == 7) ? w : (t2 + 4);
      stepA(t2, tn, K1, K0, b0, b1, a0, a1);
    }
  }

  // reduce sums: 16-lane groups, then across 4 waves
#pragma unroll
  for (int mi = 0; mi < 4; ++mi)
#pragma unroll
    for (int r = 0; r < 4; ++r) {
      float s = ls[mi][r];
      s += __shfl_xor(s, 1);
      s += __shfl_xor(s, 2);
      s += __shfl_xor(s, 4);
      s += __shfl_xor(s, 8);
      if (l15 == 0) redL[w][16 * mi + 4 * g + r] = s;
    }
  __syncthreads();
  if (tid < 64)
    rinvL[tid] = 1.0f / (redL[0][tid] + redL[1][tid] + redL[2][tid] + redL[3][tid]);
  __syncthreads();

  float rinv_[4][4];
#pragma unroll
  for (int mi = 0; mi < 4; ++mi)
#pragma unroll
    for (int r = 0; r < 4; ++r) rinv_[mi][r] = rinvL[16 * mi + 4 * g + r];

  // ---------------- pass B: recompute S, write attn (nt), accumulate O = P*V ----------------
  f32x4 oacc[4][4] = {};
  auto stepB = [&](int t, int tn, unsigned short* KBc, unsigned short* KBn,
                   int mk0c, int mk1c, int& mk0n, int& mk1n) {
    // counted wait: drains the 10 oldest (K/mask/V prefetch from last step);
    // the 32 newest (last step's attn stores) may stay in flight.
    asm volatile("s_waitcnt vmcnt(32)" ::: "memory");
    const int k0 = t * 32;
    short8t kf[2][2], vf[4];
#pragma unroll
    for (int ni = 0; ni < 2; ++ni)
#pragma unroll
      for (int h = 0; h < 2; ++h) {
        int row = 16 * ni + l15;
        int col = (32 * h + 8 * g) ^ ((l15 & 3) << 4);
        kf[ni][h] = *(const short8t*)(KBc + row * 64 + col);
      }
#pragma unroll
    for (int ni = 0; ni < 4; ++ni)
      vf[ni] = *(const short8t*)(VB + (16 * ni + l15) * 32 + ((8 * g) ^ ((l & 1) << 4)));
    // HAZARD FENCE: vf/kf must be register-resident before loadV may overwrite VB.
    // lgkmcnt(0) waits the ds_reads; sched_barrier stops the compiler sinking them
    // below the prefetch (rule #18).
    asm volatile("s_waitcnt lgkmcnt(0)" ::: "memory");
    __builtin_amdgcn_sched_barrier(0);

    // prefetch next tile (K double-buffered; V safe now)
    loadK(tn * 32, KBn);
    mk0n = maskb[tn * 32 + l15];
    mk1n = maskb[tn * 32 + 16 + l15];
    loadV(tn * 32);

    f32x4 sacc[4][2] = {};
#pragma unroll
    for (int mi = 0; mi < 4; ++mi)
#pragma unroll
      for (int ni = 0; ni < 2; ++ni)
#pragma unroll
        for (int h = 0; h < 2; ++h)
          sacc[mi][ni] = __builtin_amdgcn_mfma_f32_16x16x32_bf16(qf[mi][h], kf[ni][h], sacc[mi][ni], 0, 0, 0);

#pragma unroll
    for (int mi = 0; mi < 4; ++mi)
#pragma unroll
      for (int ni = 0; ni < 2; ++ni) {
        int mk = ni ? mk1c : mk0c;
#pragma unroll
        for (int r = 0; r < 4; ++r) {
          float p = mk ? 0.f : __expf(sacc[mi][ni][r] * 0.125f) * rinv_[mi][r];
          int qloc = 16 * mi + 4 * g + r;
          __builtin_nontemporal_store(p, &attn[((size_t)(b * LL + q0 + qloc)) * LL + k0 + 16 * ni + l15]);
          PB[qloc * 32 + ((16 * ni + l15) ^ ((r & 1) << 4))] = f2bf(p);
        }
      }

    short8t pf[4];
#pragma unroll
    for (int mi = 0; mi < 4; ++mi)
      pf[mi] = *(const short8t*)(PB + (16 * mi + l15) * 32 + ((8 * g) ^ ((l & 1) << 4)));
#pragma unroll
    for (int mi = 0; mi < 4; ++mi)
#pragma unroll
      for (int ni = 0; ni < 4; ++ni)
        oacc[mi][ni] = __builtin_amdgcn_mfma_f32_16x16x32_bf16(pf[mi], vf[ni], oacc[mi][ni], 0, 0, 0);
  };

  {
    loadK(w * 32, K0);
    int a0 = maskb[w * 32 + l15], a1 = maskb[w * 32 + 16 + l15];
    loadV(w * 32);
    asm volatile("s_waitcnt vmcnt(0)" ::: "memory");
    int b0, b1;
    for (int j = 0; j < 8; ++j) {
      int t = w + 8 * j;
      stepB(t, t + 4, K0, K1, a0, a1, b0, b1);
      int t2 = t + 4;
      int tn = (j == 7) ? w : (t2 + 4);
      stepB(t2, tn, K1, K0, b0, b1, a0, a1);
    }
  }

  // EPILOGUE DRAIN: the tail step's prefetch glds are still in flight and write
  // into TB, which we are about to reuse as float scratch. Drain before barrier.
  asm volatile("s_waitcnt vmcnt(0)" ::: "memory");

  // cross-wave O reduction (waves held disjoint k-stripes)
  __syncthreads();
  float* OB = (float*)&TB[0][0];
  if (w) {
#pragma unroll
    for (int mi = 0; mi < 4; ++mi)
#pragma unroll
      for (int ni = 0; ni < 4; ++ni)
#pragma unroll
        for (int r = 0; r < 4; ++r)
          OB[(w - 1) * 4096 + (16 * mi + 4 * g + r) * 64 + 16 * ni + l15] = oacc[mi][ni][r];
  }
  __syncthreads();
  if (w == 0) {
#pragma unroll
    for (int mi = 0; mi < 4; ++mi)
#pragma unroll
      for (int ni = 0; ni < 4; ++ni)
#pragma unroll
        for (int r = 0; r < 4; ++r) {
          int pos = (16 * mi + 4 * g + r) * 64 + 16 * ni + l15;
          float o = oacc[mi][ni][r] + OB[pos] + OB[4096 + pos] + OB[8192 + pos];
          out[((size_t)(b * LL + q0 + 16 * mi + 4 * g + r)) * DD + 16 * ni + l15] = o;
        }
  }
}

extern "C" void kernel_launch(void* const* d_in, const int* in_sizes, int n_in,
                              void* d_out, int out_size, void* d_ws, size_t ws_size,
                              hipStream_t stream) {
  const float* q = (const float*)d_in[0];
  const float* k = (const float*)d_in[1];
  const float* v = (const float*)d_in[2];
  const int* pm = (const int*)d_in[3];

  float* out = (float*)d_out;
  float* attn = out + (size_t)BB * LL * DD;

  unsigned short* Qb = (unsigned short*)d_ws;
  unsigned short* Kb = Qb + (size_t)BB * LL * DD;
  unsigned short* VT = Kb + (size_t)BB * LL * DD;

  cvt_bf16<<<2048, 256, 0, stream>>>(q, Qb);
  cvt_bf16<<<2048, 256, 0, stream>>>(k, Kb);
  vtrans<<<512, 256, 0, stream>>>(v, VT);
  attn_main<<<512, 256, 0, stream>>>(Qb, Kb, VT, pm, out, attn);
}

// Round 4
// 94.715 us; speedup vs baseline: 1.2294x; 1.2294x over previous
//
#include <hip/hip_runtime.h>
#include <hip/hip_bf16.h>

#define BB 16
#define LL 2048
#define DD 64

typedef __attribute__((ext_vector_type(8))) short short8t;
typedef __attribute__((ext_vector_type(4))) float f32x4;
typedef __attribute__((ext_vector_type(4))) unsigned short ushort4t;

__device__ __forceinline__ unsigned short f2bf(float x) {
  union { float f; unsigned int u; } c; c.f = x;
  unsigned int u = c.u;
  u += 0x7fffu + ((u >> 16) & 1u);   // RNE; inputs are finite
  return (unsigned short)(u >> 16);
}

// fp32 -> bf16 elementwise (2M elements per tensor)
__global__ void cvt_bf16(const float* __restrict__ in, unsigned short* __restrict__ out) {
  int i = (blockIdx.x * 256 + threadIdx.x) * 4;
  float4 v = *(const float4*)(in + i);
  ushort4t o;
  o.x = f2bf(v.x); o.y = f2bf(v.y); o.z = f2bf(v.z); o.w = f2bf(v.w);
  *(ushort4t*)(out + i) = o;
}

// V [b][j][d] fp32 -> VT [b][d][j] bf16 (64x64 LDS tile transpose)
__global__ void vtrans(const float* __restrict__ v, unsigned short* __restrict__ vt) {
  __shared__ unsigned short t[64][66];
  int b = blockIdx.x >> 5, j0 = (blockIdx.x & 31) * 64;
  const float* src = v + ((size_t)b * LL + j0) * DD;
#pragma unroll
  for (int i = 0; i < 16; ++i) {
    int lin = i * 256 + threadIdx.x;
    int j = lin >> 6, d = lin & 63;
    t[j][d] = f2bf(src[lin]);
  }
  __syncthreads();
  unsigned short* dst = vt + (size_t)b * DD * LL;
#pragma unroll
  for (int i = 0; i < 16; ++i) {
    int lin = i * 256 + threadIdx.x;
    int d = lin >> 6, j = lin & 63;
    dst[(size_t)d * LL + j0 + j] = t[j][d];
  }
}

__device__ __forceinline__ void async_cp16(const unsigned short* src, unsigned short* dst_lds) {
  __builtin_amdgcn_global_load_lds(
      (const __attribute__((address_space(1))) unsigned int*)src,
      (__attribute__((address_space(3))) unsigned int*)dst_lds, 16, 0, 0);
}

// Block: 4 waves, 64 queries; each wave: all 64 q x its k-stripe (16 tiles of BK=32).
// Wave-private LDS; K AND V double-buffered (no fence needed); counted vmcnt leaves
// attn stores in flight across steps. 80KB LDS/block -> 2 blocks/CU.
__global__ void __launch_bounds__(256, 2)
attn_main(const unsigned short* __restrict__ Qb, const unsigned short* __restrict__ Kb,
          const unsigned short* __restrict__ VTb, const int* __restrict__ mask,
          float* __restrict__ out, float* __restrict__ attn) {
  // per wave (shorts): K0 @0, K1 @2048, V0 @4096, V1 @6144, PB @8192  (20KB)
  __shared__ __align__(16) unsigned short TB[4][10240];
  // redL/rinvL overlay wave-0's PB region (PB unused during pass A)
  float* redF = (float*)&TB[0][8192];   // redF[0..255] = redL[4][64]
  float* rinvF = redF + 256;            // rinvF[0..63]

  const int tid = threadIdx.x;
  const int w = tid >> 6;
  const int l = tid & 63;
  const int l15 = l & 15;
  const int g = l >> 4;

  // XCD-bijective swizzle (512 % 8 == 0): each XCD owns 64 consecutive work ids
  // = 2 whole batches -> K/V resident in that XCD's private L2.
  const int swz = (blockIdx.x & 7) * 64 + (blockIdx.x >> 3);
  const int b = swz >> 5;
  const int q0 = (swz & 31) << 6;

  unsigned short* K0 = &TB[w][0];
  unsigned short* K1 = &TB[w][2048];
  unsigned short* V0 = &TB[w][4096];
  unsigned short* V1 = &TB[w][6144];
  unsigned short* PB = &TB[w][8192];

  const unsigned short* Kbb = Kb + (size_t)b * LL * DD;
  const unsigned short* VTbb = VTb + (size_t)b * DD * LL;
  const int* maskb = mask + b * LL;

  auto loadK = [&](int k0, unsigned short* KB) {
    const unsigned short* gs = Kbb + (size_t)k0 * DD;
#pragma unroll
    for (int i2 = 0; i2 < 4; ++i2) {
      int row = i2 * 8 + (l >> 3);
      int ce = (l & 7) * 8;
      async_cp16(gs + row * 64 + (ce ^ ((row & 3) << 4)), KB + i2 * 512);
    }
  };
  auto loadV = [&](int k0, unsigned short* VB) {
    const unsigned short* gs = VTbb + k0;
#pragma unroll
    for (int i2 = 0; i2 < 4; ++i2) {
      int row = i2 * 16 + (l >> 2);
      int ce = (l & 3) * 8;
      async_cp16(gs + (size_t)row * LL + (ce ^ ((row & 1) << 4)), VB + i2 * 512);
    }
  };

  // persistent Q fragments: row = q0+16*mi+l15, d = 32*h + 8*g + e
  short8t qf[4][2];
  {
    const unsigned short* qbase = Qb + ((size_t)b * LL + q0 + l15) * DD + 8 * g;
#pragma unroll
    for (int mi = 0; mi < 4; ++mi)
#pragma unroll
      for (int h = 0; h < 2; ++h)
        qf[mi][h] = *(const short8t*)(qbase + mi * 16 * DD + 32 * h);
  }

  float ls[4][4];
#pragma unroll
  for (int mi = 0; mi < 4; ++mi)
#pragma unroll
    for (int r = 0; r < 4; ++r) ls[mi][r] = 0.f;

  // ---------------- pass A: row sums of exp(s) ----------------
  auto stepA = [&](int t, int tn, unsigned short* KBc, unsigned short* KBn,
                   int mk0c, int mk1c, int& mk0n, int& mk1n) {
    asm volatile("s_waitcnt vmcnt(0)" ::: "memory");
    loadK(tn * 32, KBn);
    mk0n = maskb[tn * 32 + l15];
    mk1n = maskb[tn * 32 + 16 + l15];

    short8t kf[2][2];
#pragma unroll
    for (int ni = 0; ni < 2; ++ni)
#pragma unroll
      for (int h = 0; h < 2; ++h) {
        int row = 16 * ni + l15;
        int col = (32 * h + 8 * g) ^ ((l15 & 3) << 4);
        kf[ni][h] = *(const short8t*)(KBc + row * 64 + col);
      }

    f32x4 sacc[4][2] = {};
    __builtin_amdgcn_s_setprio(1);
#pragma unroll
    for (int mi = 0; mi < 4; ++mi)
#pragma unroll
      for (int ni = 0; ni < 2; ++ni)
#pragma unroll
        for (int h = 0; h < 2; ++h)
          sacc[mi][ni] = __builtin_amdgcn_mfma_f32_16x16x32_bf16(qf[mi][h], kf[ni][h], sacc[mi][ni], 0, 0, 0);
    __builtin_amdgcn_s_setprio(0);
#pragma unroll
    for (int mi = 0; mi < 4; ++mi)
#pragma unroll
      for (int ni = 0; ni < 2; ++ni) {
        int mk = ni ? mk1c : mk0c;
#pragma unroll
        for (int r = 0; r < 4; ++r) {
          float p = mk ? 0.f : __expf(sacc[mi][ni][r] * 0.125f);
          ls[mi][r] += p;
        }
      }
  };

  {
    loadK(w * 32, K0);
    int a0 = maskb[w * 32 + l15], a1 = maskb[w * 32 + 16 + l15];
    int b0, b1;
    for (int j = 0; j < 8; ++j) {
      int t = w + 8 * j;
      stepA(t, t + 4, K0, K1, a0, a1, b0, b1);
      int t2 = t + 4;
      int tn = (j == 7) ? w : (t2 + 4);
      stepA(t2, tn, K1, K0, b0, b1, a0, a1);
    }
  }

  // reduce sums: 16-lane groups, then across 4 waves (redF overlays wave-0 PB)
#pragma unroll
  for (int mi = 0; mi < 4; ++mi)
#pragma unroll
    for (int r = 0; r < 4; ++r) {
      float s = ls[mi][r];
      s += __shfl_xor(s, 1);
      s += __shfl_xor(s, 2);
      s += __shfl_xor(s, 4);
      s += __shfl_xor(s, 8);
      if (l15 == 0) redF[w * 64 + 16 * mi + 4 * g + r] = s;
    }
  __syncthreads();
  if (tid < 64)
    rinvF[tid] = 1.0f / (redF[tid] + redF[64 + tid] + redF[128 + tid] + redF[192 + tid]);
  __syncthreads();

  float rinv_[4][4];
#pragma unroll
  for (int mi = 0; mi < 4; ++mi)
#pragma unroll
    for (int r = 0; r < 4; ++r) rinv_[mi][r] = rinvF[16 * mi + 4 * g + r];
  __syncthreads();  // rinvF read complete before wave-0's PB writes may clobber it

  // ---------------- pass B: recompute S, write attn, accumulate O = P*V ----------------
  f32x4 oacc[4][4] = {};
  auto stepB = [&](int t, int tn, const unsigned short* KBc, unsigned short* KBn,
                   const unsigned short* VBc, unsigned short* VBn,
                   int mk0c, int mk1c, int& mk0n, int& mk1n) {
    // counted wait: drains only the 10 oldest (prev step's K/V/mask prefetch);
    // the 32 attn stores of the previous step stay in flight.
    asm volatile("s_waitcnt vmcnt(32)" ::: "memory");
    const int k0 = t * 32;

    // prefetch next tile into the alternate buffers (no overlap with KBc/VBc)
    loadK(tn * 32, KBn);
    loadV(tn * 32, VBn);
    mk0n = maskb[tn * 32 + l15];
    mk1n = maskb[tn * 32 + 16 + l15];

    short8t kf[2][2], vf[4];
#pragma unroll
    for (int ni = 0; ni < 2; ++ni)
#pragma unroll
      for (int h = 0; h < 2; ++h) {
        int row = 16 * ni + l15;
        int col = (32 * h + 8 * g) ^ ((l15 & 3) << 4);
        kf[ni][h] = *(const short8t*)(KBc + row * 64 + col);
      }
#pragma unroll
    for (int ni = 0; ni < 4; ++ni)
      vf[ni] = *(const short8t*)(VBc + (16 * ni + l15) * 32 + ((8 * g) ^ ((l & 1) << 4)));

    f32x4 sacc[4][2] = {};
    __builtin_amdgcn_s_setprio(1);
#pragma unroll
    for (int mi = 0; mi < 4; ++mi)
#pragma unroll
      for (int ni = 0; ni < 2; ++ni)
#pragma unroll
        for (int h = 0; h < 2; ++h)
          sacc[mi][ni] = __builtin_amdgcn_mfma_f32_16x16x32_bf16(qf[mi][h], kf[ni][h], sacc[mi][ni], 0, 0, 0);
    __builtin_amdgcn_s_setprio(0);

#pragma unroll
    for (int mi = 0; mi < 4; ++mi)
#pragma unroll
      for (int ni = 0; ni < 2; ++ni) {
        int mk = ni ? mk1c : mk0c;
#pragma unroll
        for (int r = 0; r < 4; ++r) {
          float p = mk ? 0.f : __expf(sacc[mi][ni][r] * 0.125f) * rinv_[mi][r];
          int qloc = 16 * mi + 4 * g + r;
          attn[((size_t)(b * LL + q0 + qloc)) * LL + k0 + 16 * ni + l15] = p;
          PB[qloc * 32 + ((16 * ni + l15) ^ ((r & 1) << 4))] = f2bf(p);
        }
      }

    short8t pf[4];
#pragma unroll
    for (int mi = 0; mi < 4; ++mi)
      pf[mi] = *(const short8t*)(PB + (16 * mi + l15) * 32 + ((8 * g) ^ ((l & 1) << 4)));
    __builtin_amdgcn_s_setprio(1);
#pragma unroll
    for (int mi = 0; mi < 4; ++mi)
#pragma unroll
      for (int ni = 0; ni < 4; ++ni)
        oacc[mi][ni] = __builtin_amdgcn_mfma_f32_16x16x32_bf16(pf[mi], vf[ni], oacc[mi][ni], 0, 0, 0);
    __builtin_amdgcn_s_setprio(0);
  };

  {
    loadK(w * 32, K0);
    loadV(w * 32, V0);
    int a0 = maskb[w * 32 + l15], a1 = maskb[w * 32 + 16 + l15];
    asm volatile("s_waitcnt vmcnt(0)" ::: "memory");
    int b0, b1;
    for (int j = 0; j < 8; ++j) {
      int t = w + 8 * j;
      stepB(t, t + 4, K0, K1, V0, V1, a0, a1, b0, b1);
      int t2 = t + 4;
      int tn = (j == 7) ? w : (t2 + 4);
      stepB(t2, tn, K1, K0, V1, V0, b0, b1, a0, a1);
    }
  }

  // EPILOGUE DRAIN: tail prefetch glds still write into TB; drain before LDS reuse.
  asm volatile("s_waitcnt vmcnt(0)" ::: "memory");

  // cross-wave O reduction (waves held disjoint k-stripes)
  __syncthreads();
  float* OB = (float*)&TB[0][0];
  if (w) {
#pragma unroll
    for (int mi = 0; mi < 4; ++mi)
#pragma unroll
      for (int ni = 0; ni < 4; ++ni)
#pragma unroll
        for (int r = 0; r < 4; ++r)
          OB[(w - 1) * 4096 + (16 * mi + 4 * g + r) * 64 + 16 * ni + l15] = oacc[mi][ni][r];
  }
  __syncthreads();
  if (w == 0) {
#pragma unroll
    for (int mi = 0; mi < 4; ++mi)
#pragma unroll
      for (int ni = 0; ni < 4; ++ni)
#pragma unroll
        for (int r = 0; r < 4; ++r) {
          int pos = (16 * mi + 4 * g + r) * 64 + 16 * ni + l15;
          float o = oacc[mi][ni][r] + OB[pos] + OB[4096 + pos] + OB[8192 + pos];
          out[((size_t)(b * LL + q0 + 16 * mi + 4 * g + r)) * DD + 16 * ni + l15] = o;
        }
  }
}

extern "C" void kernel_launch(void* const* d_in, const int* in_sizes, int n_in,
                              void* d_out, int out_size, void* d_ws, size_t ws_size,
                              hipStream_t stream) {
  const float* q = (const float*)d_in[0];
  const float* k = (const float*)d_in[1];
  const float* v = (const float*)d_in[2];
  const int* pm = (const int*)d_in[3];

  float* out = (float*)d_out;
  float* attn = out + (size_t)BB * LL * DD;

  unsigned short* Qb = (unsigned short*)d_ws;
  unsigned short* Kb = Qb + (size_t)BB * LL * DD;
  unsigned short* VT = Kb + (size_t)BB * LL * DD;

  cvt_bf16<<<2048, 256, 0, stream>>>(q, Qb);
  cvt_bf16<<<2048, 256, 0, stream>>>(k, Kb);
  vtrans<<<512, 256, 0, stream>>>(v, VT);
  attn_main<<<512, 256, 0, stream>>>(Qb, Kb, VT, pm, out, attn);
}

// Round 5
// 90.496 us; speedup vs baseline: 1.2867x; 1.0466x over previous
//
#include <hip/hip_runtime.h>
#include <hip/hip_bf16.h>

#define BB 16
#define LL 2048
#define DD 64

typedef __attribute__((ext_vector_type(8))) short short8t;
typedef __attribute__((ext_vector_type(4))) float f32x4;
typedef __attribute__((ext_vector_type(4))) unsigned short ushort4t;

__device__ __forceinline__ unsigned short f2bf(float x) {
  union { float f; unsigned int u; } c; c.f = x;
  unsigned int u = c.u;
  u += 0x7fffu + ((u >> 16) & 1u);   // RNE; inputs are finite
  return (unsigned short)(u >> 16);
}

// fp32 -> bf16 elementwise (2M elements per tensor)
__global__ void cvt_bf16(const float* __restrict__ in, unsigned short* __restrict__ out) {
  int i = (blockIdx.x * 256 + threadIdx.x) * 4;
  float4 v = *(const float4*)(in + i);
  ushort4t o;
  o.x = f2bf(v.x); o.y = f2bf(v.y); o.z = f2bf(v.z); o.w = f2bf(v.w);
  *(ushort4t*)(out + i) = o;
}

// V [b][j][d] fp32 -> VT [b][d][j] bf16 (64x64 LDS tile transpose)
__global__ void vtrans(const float* __restrict__ v, unsigned short* __restrict__ vt) {
  __shared__ unsigned short t[64][66];
  int b = blockIdx.x >> 5, j0 = (blockIdx.x & 31) * 64;
  const float* src = v + ((size_t)b * LL + j0) * DD;
#pragma unroll
  for (int i = 0; i < 16; ++i) {
    int lin = i * 256 + threadIdx.x;
    int j = lin >> 6, d = lin & 63;
    t[j][d] = f2bf(src[lin]);
  }
  __syncthreads();
  unsigned short* dst = vt + (size_t)b * DD * LL;
#pragma unroll
  for (int i = 0; i < 16; ++i) {
    int lin = i * 256 + threadIdx.x;
    int d = lin >> 6, j = lin & 63;
    dst[(size_t)d * LL + j0 + j] = t[j][d];
  }
}

__device__ __forceinline__ void async_cp16(const unsigned short* src, unsigned short* dst_lds) {
  __builtin_amdgcn_global_load_lds(
      (const __attribute__((address_space(1))) unsigned int*)src,
      (__attribute__((address_space(3))) unsigned int*)dst_lds, 16, 0, 0);
}

// Block: 4 waves, 64 queries; each wave: all 64 q x its k-stripe (16 tiles of BK=32).
// Wave-private LDS: K dbuf, V single (fenced), PF = f32 P-tile enabling FULL-LINE
// (float4) attn stores — kills L2 read-for-ownership on the 268MB attn write.
// 80KB LDS/block -> 2 blocks/CU.
__global__ void __launch_bounds__(256, 2)
attn_main(const unsigned short* __restrict__ Qb, const unsigned short* __restrict__ Kb,
          const unsigned short* __restrict__ VTb, const int* __restrict__ mask,
          float* __restrict__ out, float* __restrict__ attn) {
  // per wave (shorts): K0 @0, K1 @2048, VB @4096, PF(f32) @6144  (20KB)
  __shared__ __align__(16) unsigned short TB[4][10240];
  // red/rinv overlay wave-0's PF region (unused during pass A)
  float* redF = (float*)&TB[0][6144];   // 256 floats
  float* rinvF = redF + 256;            // 64 floats

  const int tid = threadIdx.x;
  const int w = tid >> 6;
  const int l = tid & 63;
  const int l15 = l & 15;
  const int g = l >> 4;

  // XCD-bijective swizzle (512 % 8 == 0): each XCD owns 2 whole batches.
  const int swzb = (blockIdx.x & 7) * 64 + (blockIdx.x >> 3);
  const int b = swzb >> 5;
  const int q0 = (swzb & 31) << 6;

  unsigned short* K0 = &TB[w][0];
  unsigned short* K1 = &TB[w][2048];
  unsigned short* VB = &TB[w][4096];
  float* PF = (float*)&TB[w][6144];     // [64][32] f32, col ^= ((q>>2)&1)<<4

  const unsigned short* Kbb = Kb + (size_t)b * LL * DD;
  const unsigned short* VTbb = VTb + (size_t)b * DD * LL;
  const int* maskb = mask + b * LL;

  auto loadK = [&](int k0, unsigned short* KB) {
    const unsigned short* gs = Kbb + (size_t)k0 * DD;
#pragma unroll
    for (int i2 = 0; i2 < 4; ++i2) {
      int row = i2 * 8 + (l >> 3);
      int ce = (l & 7) * 8;
      async_cp16(gs + row * 64 + (ce ^ ((row & 3) << 4)), KB + i2 * 512);
    }
  };
  auto loadV = [&](int k0) {
    const unsigned short* gs = VTbb + k0;
#pragma unroll
    for (int i2 = 0; i2 < 4; ++i2) {
      int row = i2 * 16 + (l >> 2);
      int ce = (l & 3) * 8;
      async_cp16(gs + (size_t)row * LL + (ce ^ ((row & 1) << 4)), VB + i2 * 512);
    }
  };

  // persistent Q fragments: row = q0+16*mi+l15, d = 32*h + 8*g + e
  short8t qf[4][2];
  {
    const unsigned short* qbase = Qb + ((size_t)b * LL + q0 + l15) * DD + 8 * g;
#pragma unroll
    for (int mi = 0; mi < 4; ++mi)
#pragma unroll
      for (int h = 0; h < 2; ++h)
        qf[mi][h] = *(const short8t*)(qbase + mi * 16 * DD + 32 * h);
  }

  float ls[4][4];
#pragma unroll
  for (int mi = 0; mi < 4; ++mi)
#pragma unroll
    for (int r = 0; r < 4; ++r) ls[mi][r] = 0.f;

  // ---------------- pass A: row sums of exp(s) ----------------
  auto stepA = [&](int t, int tn, unsigned short* KBc, unsigned short* KBn,
                   int mk0c, int mk1c, int& mk0n, int& mk1n) {
    asm volatile("s_waitcnt vmcnt(0)" ::: "memory");
    loadK(tn * 32, KBn);
    mk0n = maskb[tn * 32 + l15];
    mk1n = maskb[tn * 32 + 16 + l15];

    short8t kf[2][2];
#pragma unroll
    for (int ni = 0; ni < 2; ++ni)
#pragma unroll
      for (int h = 0; h < 2; ++h) {
        int row = 16 * ni + l15;
        int col = (32 * h + 8 * g) ^ ((l15 & 3) << 4);
        kf[ni][h] = *(const short8t*)(KBc + row * 64 + col);
      }

    f32x4 sacc[4][2] = {};
    __builtin_amdgcn_s_setprio(1);
#pragma unroll
    for (int mi = 0; mi < 4; ++mi)
#pragma unroll
      for (int ni = 0; ni < 2; ++ni)
#pragma unroll
        for (int h = 0; h < 2; ++h)
          sacc[mi][ni] = __builtin_amdgcn_mfma_f32_16x16x32_bf16(qf[mi][h], kf[ni][h], sacc[mi][ni], 0, 0, 0);
    __builtin_amdgcn_s_setprio(0);
#pragma unroll
    for (int mi = 0; mi < 4; ++mi)
#pragma unroll
      for (int ni = 0; ni < 2; ++ni) {
        int mk = ni ? mk1c : mk0c;
#pragma unroll
        for (int r = 0; r < 4; ++r) {
          float p = mk ? 0.f : __expf(sacc[mi][ni][r] * 0.125f);
          ls[mi][r] += p;
        }
      }
  };

  {
    loadK(w * 32, K0);
    int a0 = maskb[w * 32 + l15], a1 = maskb[w * 32 + 16 + l15];
    int b0, b1;
    for (int j = 0; j < 8; ++j) {
      int t = w + 8 * j;
      stepA(t, t + 4, K0, K1, a0, a1, b0, b1);
      int t2 = t + 4;
      int tn = (j == 7) ? w : (t2 + 4);
      stepA(t2, tn, K1, K0, b0, b1, a0, a1);
    }
  }

  // reduce sums: 16-lane groups, then across 4 waves (redF overlays wave-0 PF)
#pragma unroll
  for (int mi = 0; mi < 4; ++mi)
#pragma unroll
    for (int r = 0; r < 4; ++r) {
      float s = ls[mi][r];
      s += __shfl_xor(s, 1);
      s += __shfl_xor(s, 2);
      s += __shfl_xor(s, 4);
      s += __shfl_xor(s, 8);
      if (l15 == 0) redF[w * 64 + 16 * mi + 4 * g + r] = s;
    }
  __syncthreads();
  if (tid < 64)
    rinvF[tid] = 1.0f / (redF[tid] + redF[64 + tid] + redF[128 + tid] + redF[192 + tid]);
  __syncthreads();

  float rinv_[4][4];
#pragma unroll
  for (int mi = 0; mi < 4; ++mi)
#pragma unroll
    for (int r = 0; r < 4; ++r) rinv_[mi][r] = rinvF[16 * mi + 4 * g + r];
  __syncthreads();  // rinvF consumed before wave-0's PF writes clobber it

  // ---------------- pass B: recompute S, write attn (full-line), accumulate O ----------------
  f32x4 oacc[4][4] = {};
  const size_t arow = (size_t)b * LL + q0;
  auto stepB = [&](int t, int tn, const unsigned short* KBc, unsigned short* KBn,
                   int mk0c, int mk1c, int& mk0n, int& mk1n) {
    // counted wait: drains the 10 loads of the previous prefetch;
    // the 8 attn line-stores of the previous step stay in flight.
    asm volatile("s_waitcnt vmcnt(8)" ::: "memory");
    const int k0 = t * 32;

    short8t kf[2][2], vf[4];
#pragma unroll
    for (int ni = 0; ni < 2; ++ni)
#pragma unroll
      for (int h = 0; h < 2; ++h) {
        int row = 16 * ni + l15;
        int col = (32 * h + 8 * g) ^ ((l15 & 3) << 4);
        kf[ni][h] = *(const short8t*)(KBc + row * 64 + col);
      }
#pragma unroll
    for (int ni = 0; ni < 4; ++ni)
      vf[ni] = *(const short8t*)(VB + (16 * ni + l15) * 32 + ((8 * g) ^ ((l & 1) << 4)));
    // fence: vf/kf register-resident before the V prefetch may overwrite VB (rule #18)
    asm volatile("s_waitcnt lgkmcnt(0)" ::: "memory");
    __builtin_amdgcn_sched_barrier(0);

    loadK(tn * 32, KBn);
    mk0n = maskb[tn * 32 + l15];
    mk1n = maskb[tn * 32 + 16 + l15];
    loadV(tn * 32);

    f32x4 sacc[4][2] = {};
    __builtin_amdgcn_s_setprio(1);
#pragma unroll
    for (int mi = 0; mi < 4; ++mi)
#pragma unroll
      for (int ni = 0; ni < 2; ++ni)
#pragma unroll
        for (int h = 0; h < 2; ++h)
          sacc[mi][ni] = __builtin_amdgcn_mfma_f32_16x16x32_bf16(qf[mi][h], kf[ni][h], sacc[mi][ni], 0, 0, 0);
    __builtin_amdgcn_s_setprio(0);

    // P -> f32 LDS tile (conflict-free: bit4 XOR by (q>>2)&1 == g&1 here)
#pragma unroll
    for (int mi = 0; mi < 4; ++mi)
#pragma unroll
      for (int ni = 0; ni < 2; ++ni) {
        int mk = ni ? mk1c : mk0c;
#pragma unroll
        for (int r = 0; r < 4; ++r) {
          float p = mk ? 0.f : __expf(sacc[mi][ni][r] * 0.125f) * rinv_[mi][r];
          PF[(16 * mi + 4 * g + r) * 32 + ((16 * ni + l15) ^ ((g & 1) << 4))] = p;
        }
      }

    // attn store burst: 8 x float4 per lane = full 128B lines, no RFO
#pragma unroll
    for (int it = 0; it < 8; ++it) {
      int row = it * 8 + (l >> 3);
      int c4 = (l & 7) * 4;
      float4 pv = *(const float4*)(PF + row * 32 + (c4 ^ (((row >> 2) & 1) << 4)));
      *(float4*)(attn + (arow + row) * LL + k0 + c4) = pv;
    }

    // PV fragments from PF (f32 -> bf16 in regs)
    short8t pf[4];
#pragma unroll
    for (int mi = 0; mi < 4; ++mi) {
      int qq = 16 * mi + l15;
      const float* src = PF + qq * 32 + ((8 * g) ^ (((l15 >> 2) & 1) << 4));
      float4 pa = *(const float4*)(src);
      float4 pb = *(const float4*)(src + 4);
      short8t f;
      f[0] = (short)f2bf(pa.x); f[1] = (short)f2bf(pa.y);
      f[2] = (short)f2bf(pa.z); f[3] = (short)f2bf(pa.w);
      f[4] = (short)f2bf(pb.x); f[5] = (short)f2bf(pb.y);
      f[6] = (short)f2bf(pb.z); f[7] = (short)f2bf(pb.w);
      pf[mi] = f;
    }
    __builtin_amdgcn_s_setprio(1);
#pragma unroll
    for (int mi = 0; mi < 4; ++mi)
#pragma unroll
      for (int ni = 0; ni < 4; ++ni)
        oacc[mi][ni] = __builtin_amdgcn_mfma_f32_16x16x32_bf16(pf[mi], vf[ni], oacc[mi][ni], 0, 0, 0);
    __builtin_amdgcn_s_setprio(0);
  };

  {
    loadK(w * 32, K0);
    int a0 = maskb[w * 32 + l15], a1 = maskb[w * 32 + 16 + l15];
    loadV(w * 32);
    asm volatile("s_waitcnt vmcnt(0)" ::: "memory");
    int b0, b1;
    for (int j = 0; j < 8; ++j) {
      int t = w + 8 * j;
      stepB(t, t + 4, K0, K1, a0, a1, b0, b1);
      int t2 = t + 4;
      int tn = (j == 7) ? w : (t2 + 4);
      stepB(t2, tn, K1, K0, b0, b1, a0, a1);
    }
  }

  // EPILOGUE DRAIN: tail prefetch glds still write into TB; drain before LDS reuse.
  asm volatile("s_waitcnt vmcnt(0)" ::: "memory");

  // cross-wave O reduction; final out written as full-line float4 by all threads
  __syncthreads();
  float* OB = (float*)&TB[0][0];
  if (w) {
#pragma unroll
    for (int mi = 0; mi < 4; ++mi)
#pragma unroll
      for (int ni = 0; ni < 4; ++ni)
#pragma unroll
        for (int r = 0; r < 4; ++r)
          OB[(w - 1) * 4096 + (16 * mi + 4 * g + r) * 64 + 16 * ni + l15] = oacc[mi][ni][r];
  }
  __syncthreads();
  if (w == 0) {
#pragma unroll
    for (int mi = 0; mi < 4; ++mi)
#pragma unroll
      for (int ni = 0; ni < 4; ++ni)
#pragma unroll
        for (int r = 0; r < 4; ++r) {
          int pos = (16 * mi + 4 * g + r) * 64 + 16 * ni + l15;
          OB[12288 + pos] = oacc[mi][ni][r] + OB[pos] + OB[4096 + pos] + OB[8192 + pos];
        }
  }
  __syncthreads();
#pragma unroll
  for (int it = 0; it < 4; ++it) {
    int lin = it * 256 + tid;
    int row = lin >> 4;
    int c4 = (lin & 15) * 4;
    float4 o4 = *(const float4*)(OB + 12288 + row * 64 + c4);
    *(float4*)(out + ((size_t)(b * LL + q0 + row)) * DD + c4) = o4;
  }
}

extern "C" void kernel_launch(void* const* d_in, const int* in_sizes, int n_in,
                              void* d_out, int out_size, void* d_ws, size_t ws_size,
                              hipStream_t stream) {
  const float* q = (const float*)d_in[0];
  const float* k = (const float*)d_in[1];
  const float* v = (const float*)d_in[2];
  const int* pm = (const int*)d_in[3];

  float* out = (float*)d_out;
  float* attn = out + (size_t)BB * LL * DD;

  unsigned short* Qb = (unsigned short*)d_ws;
  unsigned short* Kb = Qb + (size_t)BB * LL * DD;
  unsigned short* VT = Kb + (size_t)BB * LL * DD;

  cvt_bf16<<<2048, 256, 0, stream>>>(q, Qb);
  cvt_bf16<<<2048, 256, 0, stream>>>(k, Kb);
  vtrans<<<512, 256, 0, stream>>>(v, VT);
  attn_main<<<512, 256, 0, stream>>>(Qb, Kb, VT, pm, out, attn);
}